// Round 3
// baseline (392.433 us; speedup 1.0000x reference)
//
#include <hip/hip_runtime.h>

// Problem: B=2048, H=4, D=4096, M=8, dm=512.
// s_flat[r,j] = sum_h x[b,h,m*512+c]*lW[m,h] + lb[m],
//   m=r>>8, b=(r&255)*8+(j>>9), c=j&511.
// out[r,n] = sigmoid(sum_j s_flat[r,j]*pW[n,j] + pb[n]),  out fp32 [2048][4096].
//
// R7: s-only prep (R5's win, ~53 us) + the R0 gemm structure restored exactly
// (32 KiB LDS single-buffer, 2 barriers/K-tile, 4-5 blocks/CU interleave --
// R6 post-mortem: 64 KiB LDS -> 2 blocks/CU was the regression, m132 pattern).
// Single change vs R0: B-tile staged from fp32 W via reg-loads + cvt_pk +
// swizzled ds_write (between the two barriers, sharing the existing drain
// slot), instead of gload_lds from a prep-converted bf16 copy.

#define MD 2048
#define ND 4096
#define KD 4096

typedef __attribute__((ext_vector_type(8))) __bf16 bf16x8;
typedef __attribute__((ext_vector_type(4))) float f32x4;

static __device__ __forceinline__ unsigned int f2bf(float f) {
  union { float f; unsigned int u; } v; v.f = f;
  unsigned int u = v.u;
  u += 0x7FFFu + ((u >> 16) & 1u);   // RNE
  return u >> 16;
}

// pack two floats -> 2x bf16 in a dword via native __bf16 casts (RNE; compiler
// fuses pairs into v_cvt_pk_bf16_f32 -- m240)
static __device__ __forceinline__ unsigned int pk2bf(float a, float b) {
  union { __bf16 h; unsigned short u; } x, y;
  x.h = (__bf16)a; y.h = (__bf16)b;
  return (unsigned)x.u | ((unsigned)y.u << 16);
}

// Prep (unchanged from R5/R6): s_flat only. One-shot threads, 8x16B loads in
// flight, plain cacheable loads, 16B stores. Grid 4096 blocks. ~53 us.
__global__ __launch_bounds__(256) void prep_kernel(
    const float* __restrict__ x, const float* __restrict__ lW,
    const float* __restrict__ lb, unsigned short* __restrict__ sB) {
  int g = blockIdx.x * 256 + threadIdx.x;   // 0 .. 2^20
  int j8 = g << 3;                          // flat index r*4096 + j, j8 % 8 == 0
  int r = j8 >> 12;
  int j = j8 & 4095;
  int m = r >> 8;
  int b = ((r & 255) << 3) + (j >> 9);
  int c = j & 511;                          // 8 consecutive j stay in one 512-group
  const float* xp = x + ((long)b << 14) + m * 512 + c;
  float w0 = lW[m * 4 + 0], w1 = lW[m * 4 + 1], w2 = lW[m * 4 + 2], w3 = lW[m * 4 + 3];
  float bb = lb[m];
  float4 xa0 = *(const float4*)(xp);
  float4 xb0 = *(const float4*)(xp + 4);
  float4 xa1 = *(const float4*)(xp + 4096);
  float4 xb1 = *(const float4*)(xp + 4100);
  float4 xa2 = *(const float4*)(xp + 8192);
  float4 xb2 = *(const float4*)(xp + 8196);
  float4 xa3 = *(const float4*)(xp + 12288);
  float4 xb3 = *(const float4*)(xp + 12292);
  float v0 = bb + xa0.x * w0 + xa1.x * w1 + xa2.x * w2 + xa3.x * w3;
  float v1 = bb + xa0.y * w0 + xa1.y * w1 + xa2.y * w2 + xa3.y * w3;
  float v2 = bb + xa0.z * w0 + xa1.z * w1 + xa2.z * w2 + xa3.z * w3;
  float v3 = bb + xa0.w * w0 + xa1.w * w1 + xa2.w * w2 + xa3.w * w3;
  float v4 = bb + xb0.x * w0 + xb1.x * w1 + xb2.x * w2 + xb3.x * w3;
  float v5 = bb + xb0.y * w0 + xb1.y * w1 + xb2.y * w2 + xb3.y * w3;
  float v6 = bb + xb0.z * w0 + xb1.z * w1 + xb2.z * w2 + xb3.z * w3;
  float v7 = bb + xb0.w * w0 + xb1.w * w1 + xb2.w * w2 + xb3.w * w3;
  uint4 pk;
  pk.x = f2bf(v0) | (f2bf(v1) << 16);
  pk.y = f2bf(v2) | (f2bf(v3) << 16);
  pk.z = f2bf(v4) | (f2bf(v5) << 16);
  pk.w = f2bf(v6) | (f2bf(v7) << 16);
  *(uint4*)(sB + j8) = pk;                  // 16B store
}

// GEMM: C[2048][4096] = S[2048][4096] * W[4096][4096]^T, S bf16, W fp32
// (reg-converted to bf16 during staging). 128x128 tile, BK=64, 4 waves 2x2,
// each wave 4x4 of 16x16x32 MFMA. R0 schedule:
//   barrier1; issue A gload_lds + W reg-loads; cvt W -> ds_write Bs;
//   barrier2 (drains everything, as R0 did); MFMA.
// LDS 32 KiB total (As+Bs, single-buffered) -> 4-5 blocks/CU block interleave
// is what hides the exposed drain (R0-proven; R5/R6 lost it at 64 KiB).
//
// Swizzle (both sides, R0/R6-proven): linear [row][64] ushorts, physical 16B
// chunk = logical kc ^ (row&7). As filled by gload_lds with the swizzle
// pre-applied to the per-lane GLOBAL src (m173). Bs filled by ds_write_b128
// with write-side XOR. Fragment reads identical to R0 (0 bank conflicts).
#define BM 128
#define BN 128
#define BK 64

__global__ __launch_bounds__(256) void gemm_kernel(
    const unsigned short* __restrict__ S, const float* __restrict__ W,
    const float* __restrict__ pb, float* __restrict__ out) {
  __shared__ unsigned short As[BM * BK];   // 16 KiB
  __shared__ unsigned short Bs[BN * BK];   // 16 KiB
  int tid = threadIdx.x;
  int lane = tid & 63;
  int wave = tid >> 6;
  int n0 = blockIdx.x * BN;   // 32 n-tiles
  int r0 = blockIdx.y * BM;   // 16 m-tiles
  int wr = wave >> 1, wc = wave & 1;

  // ---- A staging (global_load_lds, src-swizzled, linear dest) -- as R0
  int srow = (wave << 5) + (lane >> 3);            // + i*8 per issue
  int scol = (((lane & 7) ^ (lane >> 3)) << 3);    // swizzled k-element offset
  const unsigned short* gA = S + (long)(r0 + srow) * KD + scol;
  unsigned short* lA = &As[(wave << 5) * BK];  // wave-uniform base; HW adds lane*16B

  // ---- W reg-staging: thread -> row = tid>>1, k-half = tid&1 (32 consec k)
  int brow = tid >> 1;
  int bk0 = (tid & 1) << 5;
  const float* gW = W + (long)(n0 + brow) * KD + bk0;
  unsigned short* wBs = &Bs[brow * BK];
  int bsw = brow & 7;
  int kcb = (tid & 1) << 2;     // 16B-chunk base: kc = kcb + q2

  f32x4 acc[4][4] = {};

  for (int kt = 0; kt < KD; kt += BK) {
    __syncthreads();   // barrier1: all waves done reading As/Bs of prev tile
#pragma unroll
    for (int i = 0; i < 4; ++i)
      __builtin_amdgcn_global_load_lds(
          (const __attribute__((address_space(1))) unsigned int*)(gA + (long)i * 8 * KD + kt),
          (__attribute__((address_space(3))) unsigned int*)(lA + i * 8 * BK), 16, 0, 0);
    // W loads for this tile: in flight together with the A gloads; the cvt's
    // wv wait shares the drain slot barrier2 would pay anyway (R0 pattern).
    f32x4 wv[8];
#pragma unroll
    for (int q = 0; q < 8; ++q)
      wv[q] = *(const f32x4*)(gW + kt + q * 4);
#pragma unroll
    for (int q2 = 0; q2 < 4; ++q2) {
      f32x4 u = wv[2 * q2], v = wv[2 * q2 + 1];
      uint4 pk;
      pk.x = pk2bf(u[0], u[1]);
      pk.y = pk2bf(u[2], u[3]);
      pk.z = pk2bf(v[0], v[1]);
      pk.w = pk2bf(v[2], v[3]);
      // balanced banks: per instr, 8 lanes per 4-bank window = minimum cycles
      *(uint4*)&wBs[((kcb + q2) ^ bsw) << 3] = pk;
    }
    __syncthreads();   // barrier2: drains A gloads (vmcnt0) + Bs writes (lgkm0)
#pragma unroll
    for (int ks = 0; ks < 2; ++ks) {
      // fragment chunk kc_lin = ks*4 + (lane>>4); physical chunk =
      // kc_lin ^ (row & 7); row&7 == lane&7 for all t (t*16 is 0 mod 8).
      int swz = (((ks << 2) + (lane >> 4)) ^ (lane & 7)) << 3;
      bf16x8 af[4], bfr[4];
#pragma unroll
      for (int t = 0; t < 4; ++t) {
        af[t]  = *(const bf16x8*)&As[((wr << 6) + t * 16 + (lane & 15)) * BK + swz];
        bfr[t] = *(const bf16x8*)&Bs[((wc << 6) + t * 16 + (lane & 15)) * BK + swz];
      }
#pragma unroll
      for (int mt = 0; mt < 4; ++mt)
#pragma unroll
        for (int nt = 0; nt < 4; ++nt)
          acc[mt][nt] = __builtin_amdgcn_mfma_f32_16x16x32_bf16(af[mt], bfr[nt], acc[mt][nt], 0, 0, 0);
    }
  }

  // epilogue: C/D layout col=lane&15, row=(lane>>4)*4+i  [m89/m91]
#pragma unroll
  for (int nt = 0; nt < 4; ++nt) {
    int col = n0 + (wc << 6) + nt * 16 + (lane & 15);
    float pbv = pb[col];
#pragma unroll
    for (int mt = 0; mt < 4; ++mt) {
      int row = r0 + (wr << 6) + mt * 16 + ((lane >> 4) << 2);
#pragma unroll
      for (int i = 0; i < 4; ++i) {
        float v = acc[mt][nt][i] + pbv;
        out[(long)(row + i) * ND + col] = 1.0f / (1.0f + __expf(-v));
      }
    }
  }
}

extern "C" void kernel_launch(void* const* d_in, const int* in_sizes, int n_in,
                              void* d_out, int out_size, void* d_ws, size_t ws_size,
                              hipStream_t stream) {
  const float* x  = (const float*)d_in[0];   // (2048, 4, 4096)
  const float* lW = (const float*)d_in[1];   // (8, 4)
  const float* lb = (const float*)d_in[2];   // (8,)
  const float* pW = (const float*)d_in[3];   // (4096, 4096)
  const float* pb = (const float*)d_in[4];   // (4096,)
  float* out = (float*)d_out;                // (2048, 4096) fp32

  unsigned short* sB = (unsigned short*)d_ws;          // 2048*4096 bf16 = 16 MiB

  prep_kernel<<<4096, 256, 0, stream>>>(x, lW, lb, sB);
  gemm_kernel<<<dim3(32, 16), 256, 0, stream>>>(sB, pW, pb, out);
}

// Round 4
// 321.843 us; speedup vs baseline: 1.2193x; 1.2193x over previous
//
#include <hip/hip_runtime.h>

// Problem: B=2048, H=4, D=4096, M=8, dm=512.
// s_flat[r,j] = sum_h x[b,h,m*512+c]*lW[m,h] + lb[m],
//   m=r>>8, b=(r&255)*8+(j>>9), c=j&511.
// out[r,n] = sigmoid(sum_j s_flat[r,j]*pW[n,j] + pb[n]),  out fp32 [2048][4096].
//
// R8: FULL REVERT to the round-0 pair (prep converts both s_flat and pW to
// bf16; gemm consumes bf16 via pure global_load_lds staging). R5/R6/R7 all
// regressed by moving W-conversion into the gemm: any reg-return (flat load ->
// vmcnt wait -> cvt -> ds_write) inserts a ~900cy serial dependency that the
// 2-blocks/CU interleave (grid 512 caps occupancy at 25% regardless of LDS)
// cannot hide. The R0 schedule's staging is waitcnt-free until barrier2.
// Single new change vs R0: T1 XCD-aware block swizzle on the gemm grid
// (hw bid b -> XCD b%8; wg = (b%8)*64 + b/8 gives each XCD 2 contiguous
// A-panel rows -> A panels stay hot in the XCD-private L2). Bijective since
// nwg=512 % 8 == 0. Pure tile remap, correctness-invariant.

#define MD 2048
#define ND 4096
#define KD 4096

typedef __attribute__((ext_vector_type(8))) __bf16 bf16x8;
typedef __attribute__((ext_vector_type(4))) float f32x4;

static __device__ __forceinline__ unsigned short f2bf(float f) {
  union { float f; unsigned int u; } v; v.f = f;
  unsigned int u = v.u;
  u += 0x7FFFu + ((u >> 16) & 1u);   // RNE
  return (unsigned short)(u >> 16);
}

// Prep v3 (R0-exact): one-shot threads, 8x16B loads in flight, plain
// cacheable loads, 16B stores.
// blocks [0,4096): s_flat (bf16), 8 j's per thread.
// blocks [4096,8192): proj_W fp32 -> bf16, 16 floats per thread.
__global__ __launch_bounds__(256) void prep_kernel(
    const float* __restrict__ x, const float* __restrict__ lW,
    const float* __restrict__ lb, const float* __restrict__ pW,
    unsigned short* __restrict__ sB, unsigned short* __restrict__ wB) {
  int bid = blockIdx.x;
  int tid = threadIdx.x;
  if (bid < 4096) {
    int g = bid * 256 + tid;                  // 0 .. 2^20
    int j8 = g << 3;                          // flat index r*4096 + j, j8 % 8 == 0
    int r = j8 >> 12;
    int j = j8 & 4095;
    int m = r >> 8;
    int b = ((r & 255) << 3) + (j >> 9);
    int c = j & 511;                          // 8 consecutive j stay in one 512-group
    const float* xp = x + ((long)b << 14) + m * 512 + c;
    float w0 = lW[m * 4 + 0], w1 = lW[m * 4 + 1], w2 = lW[m * 4 + 2], w3 = lW[m * 4 + 3];
    float bb = lb[m];
    float4 xa0 = *(const float4*)(xp);
    float4 xb0 = *(const float4*)(xp + 4);
    float4 xa1 = *(const float4*)(xp + 4096);
    float4 xb1 = *(const float4*)(xp + 4100);
    float4 xa2 = *(const float4*)(xp + 8192);
    float4 xb2 = *(const float4*)(xp + 8196);
    float4 xa3 = *(const float4*)(xp + 12288);
    float4 xb3 = *(const float4*)(xp + 12292);
    float v0 = bb + xa0.x * w0 + xa1.x * w1 + xa2.x * w2 + xa3.x * w3;
    float v1 = bb + xa0.y * w0 + xa1.y * w1 + xa2.y * w2 + xa3.y * w3;
    float v2 = bb + xa0.z * w0 + xa1.z * w1 + xa2.z * w2 + xa3.z * w3;
    float v3 = bb + xa0.w * w0 + xa1.w * w1 + xa2.w * w2 + xa3.w * w3;
    float v4 = bb + xb0.x * w0 + xb1.x * w1 + xb2.x * w2 + xb3.x * w3;
    float v5 = bb + xb0.y * w0 + xb1.y * w1 + xb2.y * w2 + xb3.y * w3;
    float v6 = bb + xb0.z * w0 + xb1.z * w1 + xb2.z * w2 + xb3.z * w3;
    float v7 = bb + xb0.w * w0 + xb1.w * w1 + xb2.w * w2 + xb3.w * w3;
    uint4 pk;
    pk.x = (unsigned)f2bf(v0) | ((unsigned)f2bf(v1) << 16);
    pk.y = (unsigned)f2bf(v2) | ((unsigned)f2bf(v3) << 16);
    pk.z = (unsigned)f2bf(v4) | ((unsigned)f2bf(v5) << 16);
    pk.w = (unsigned)f2bf(v6) | ((unsigned)f2bf(v7) << 16);
    *(uint4*)(sB + j8) = pk;                  // 16B store
  } else {
    int g = (bid - 4096) * 256 + tid;         // 0 .. 2^20, x16 floats
    long off = (long)g << 4;
    float4 a = *(const float4*)(pW + off);
    float4 b4 = *(const float4*)(pW + off + 4);
    float4 c4 = *(const float4*)(pW + off + 8);
    float4 d4 = *(const float4*)(pW + off + 12);
    uint4 p0, p1;
    p0.x = (unsigned)f2bf(a.x) | ((unsigned)f2bf(a.y) << 16);
    p0.y = (unsigned)f2bf(a.z) | ((unsigned)f2bf(a.w) << 16);
    p0.z = (unsigned)f2bf(b4.x) | ((unsigned)f2bf(b4.y) << 16);
    p0.w = (unsigned)f2bf(b4.z) | ((unsigned)f2bf(b4.w) << 16);
    p1.x = (unsigned)f2bf(c4.x) | ((unsigned)f2bf(c4.y) << 16);
    p1.y = (unsigned)f2bf(c4.z) | ((unsigned)f2bf(c4.w) << 16);
    p1.z = (unsigned)f2bf(d4.x) | ((unsigned)f2bf(d4.y) << 16);
    p1.w = (unsigned)f2bf(d4.z) | ((unsigned)f2bf(d4.w) << 16);
    *(uint4*)(wB + off) = p0;
    *(uint4*)(wB + off + 8) = p1;
  }
}

// m97-recipe GEMM (R0-exact schedule): C[2048][4096] = S * W^T (both bf16,
// K contiguous), epilogue sigmoid(acc + pb[n]) -> fp32.
// 128x128 block tile, BK=64, 4 waves in 2x2, each wave 4x4 of 16x16x32 MFMA.
// LDS [row][64] ushorts with XOR 16B-chunk swizzle (phys = kc ^ (row&7)),
// filled by global_load_lds with the swizzle pre-applied to the per-lane
// GLOBAL source address (m173 pattern). Fragment reads: 0 bank conflicts.
#define BM 128
#define BN 128
#define BK 64

__global__ __launch_bounds__(256) void gemm_kernel(
    const unsigned short* __restrict__ S, const unsigned short* __restrict__ W,
    const float* __restrict__ pb, float* __restrict__ out) {
  __shared__ unsigned short As[BM * BK];   // unpadded (global_load_lds)
  __shared__ unsigned short Bs[BN * BK];
  int tid = threadIdx.x;
  int lane = tid & 63;
  int wave = tid >> 6;

  // T1 XCD swizzle: hw bid b -> XCD b%8. wg = (b%8)*64 + b/8 gives XCD j the
  // contiguous logical tiles [64j, 64j+64) = 2 full A-panel rows (32 n-tiles
  // each) -> A panel (1 MiB) stays hot in the XCD-private L2. Bijective: 512%8==0.
  int orig = blockIdx.x;                     // 0..511
  int wg = ((orig & 7) << 6) + (orig >> 3);
  int n0 = (wg & 31) * BN;                   // 32 n-tiles (fastest within XCD chunk)
  int r0 = (wg >> 5) * BM;                   // 16 m-tiles
  int wr = wave >> 1, wc = wave & 1;

  int srow = (wave << 5) + (lane >> 3);            // + i*8 per issue
  int scol = (((lane & 7) ^ (lane >> 3)) << 3);    // swizzled k-element offset
  const unsigned short* gA = S + (long)(r0 + srow) * KD + scol;
  const unsigned short* gB = W + (long)(n0 + srow) * KD + scol;
  unsigned short* lA = &As[(wave << 5) * BK];  // wave-uniform base; HW adds lane*16B
  unsigned short* lB = &Bs[(wave << 5) * BK];

  f32x4 acc[4][4] = {};

  for (int kt = 0; kt < KD; kt += BK) {
    __syncthreads();
#pragma unroll
    for (int i = 0; i < 4; ++i) {
      __builtin_amdgcn_global_load_lds(
          (const __attribute__((address_space(1))) unsigned int*)(gA + (long)i * 8 * KD + kt),
          (__attribute__((address_space(3))) unsigned int*)(lA + i * 8 * BK), 16, 0, 0);
      __builtin_amdgcn_global_load_lds(
          (const __attribute__((address_space(1))) unsigned int*)(gB + (long)i * 8 * KD + kt),
          (__attribute__((address_space(3))) unsigned int*)(lB + i * 8 * BK), 16, 0, 0);
    }
    __syncthreads();
#pragma unroll
    for (int ks = 0; ks < 2; ++ks) {
      // fragment chunk kc_lin = ks*4 + (lane>>4); physical chunk =
      // kc_lin ^ (row & 7); row&7 == lane&7 for all t (t*16 is 0 mod 8).
      int swz = (((ks << 2) + (lane >> 4)) ^ (lane & 7)) << 3;
      bf16x8 af[4], bfr[4];
#pragma unroll
      for (int t = 0; t < 4; ++t) {
        af[t]  = *(const bf16x8*)&As[((wr << 6) + t * 16 + (lane & 15)) * BK + swz];
        bfr[t] = *(const bf16x8*)&Bs[((wc << 6) + t * 16 + (lane & 15)) * BK + swz];
      }
#pragma unroll
      for (int mt = 0; mt < 4; ++mt)
#pragma unroll
        for (int nt = 0; nt < 4; ++nt)
          acc[mt][nt] = __builtin_amdgcn_mfma_f32_16x16x32_bf16(af[mt], bfr[nt], acc[mt][nt], 0, 0, 0);
    }
  }

  // epilogue: C/D layout col=lane&15, row=(lane>>4)*4+i  [m89/m91]
#pragma unroll
  for (int nt = 0; nt < 4; ++nt) {
    int col = n0 + (wc << 6) + nt * 16 + (lane & 15);
    float pbv = pb[col];
#pragma unroll
    for (int mt = 0; mt < 4; ++mt) {
      int row = r0 + (wr << 6) + mt * 16 + ((lane >> 4) << 2);
#pragma unroll
      for (int i = 0; i < 4; ++i) {
        float v = acc[mt][nt][i] + pbv;
        out[(long)(row + i) * ND + col] = 1.0f / (1.0f + __expf(-v));
      }
    }
  }
}

extern "C" void kernel_launch(void* const* d_in, const int* in_sizes, int n_in,
                              void* d_out, int out_size, void* d_ws, size_t ws_size,
                              hipStream_t stream) {
  const float* x  = (const float*)d_in[0];   // (2048, 4, 4096)
  const float* lW = (const float*)d_in[1];   // (8, 4)
  const float* lb = (const float*)d_in[2];   // (8,)
  const float* pW = (const float*)d_in[3];   // (4096, 4096)
  const float* pb = (const float*)d_in[4];   // (4096,)
  float* out = (float*)d_out;                // (2048, 4096) fp32

  unsigned short* sB = (unsigned short*)d_ws;          // 2048*4096 bf16 = 16 MiB
  unsigned short* wB = sB + (long)MD * KD;             // 4096*4096 bf16 = 32 MiB

  prep_kernel<<<8192, 256, 0, stream>>>(x, lW, lb, pW, sB, wB);
  gemm_kernel<<<512, 256, 0, stream>>>(sB, wB, pb, out);
}